// Round 1
// baseline (3327.499 us; speedup 1.0000x reference)
//
#include <hip/hip_runtime.h>
#include <array>

#define DEV __device__ __forceinline__

// ---------------------------------------------------------------------------
// Compile-time real Clebsch-Gordan tables (mirror of reference _build_paths)
// ---------------------------------------------------------------------------
namespace cgt {

constexpr double FACT[14] = {1.,1.,2.,6.,24.,120.,720.,5040.,40320.,362880.,
                             3628800.,39916800.,479001600.,6227020800.};

constexpr double csqrt(double x){
  if(x <= 0.0) return 0.0;
  double g = x > 1.0 ? x : 1.0;
  for(int i=0;i<28;++i) g = 0.5*(g + x/g);
  return g;
}

constexpr double cgc(int l1,int m1,int l2,int m2,int l3,int m3){
  if(m3 != m1+m2) return 0.0;
  double pre = (2.0*l3+1.0)*FACT[l1+l2-l3]*FACT[l1-l2+l3]*FACT[-l1+l2+l3]/FACT[l1+l2+l3+1];
  pre = csqrt(pre * FACT[l1+m1]*FACT[l1-m1]*FACT[l2+m2]*FACT[l2-m2]*FACT[l3+m3]*FACT[l3-m3]);
  double s = 0.0;
  for(int k=0;k<=l1+l2-l3;++k){
    int d1=l1+l2-l3-k, d2=l1-m1-k, d3=l2+m2-k, d4=l3-l2+m1+k, d5=l3-l1-m2+k;
    if(d1<0||d2<0||d3<0||d4<0||d5<0) continue;
    double den = FACT[k]*FACT[d1]*FACT[d2]*FACT[d3]*FACT[d4]*FACT[d5];
    s += ((k&1)? -1.0 : 1.0)/den;
  }
  return pre*s;
}

struct C2 { double re, im; };

// U_l[a, m+l] of the complex->real SH change of basis
constexpr C2 uent(int l, int a, int m){
  const double s = 0.70710678118654752440;
  int mr = a - l;
  if(mr == 0) return (m==0) ? C2{1.0,0.0} : C2{0.0,0.0};
  if(mr > 0){
    if(m ==  mr) return C2{ (mr&1)? -s : s, 0.0};
    if(m == -mr) return C2{ s, 0.0};
    return C2{0.0,0.0};
  }
  if(m ==  mr) return C2{0.0, s};
  if(m == -mr) return C2{0.0, ((-mr)&1)? s : -s};
  return C2{0.0,0.0};
}

constexpr float crent(int l1,int l2,int l3,int a,int b,int c){
  double re = 0.0;
  int mrc = c - l3;
  for(int i=0;i<2;++i){
    if(i==1 && a==l1) break;
    int m1 = (i==0) ? (a-l1) : (l1-a);
    for(int j=0;j<2;++j){
      if(j==1 && b==l2) break;
      int m2 = (j==0) ? (b-l2) : (l2-b);
      int m3 = m1+m2;
      if(m3 < -l3 || m3 > l3) continue;
      if(m3 != mrc && m3 != -mrc) continue;   // U3 row-c sparsity
      C2 u1 = uent(l1,a,m1), u2 = uent(l2,b,m2), u3 = uent(l3,c,m3);
      double u3re = u3.re, u3im = -u3.im;     // conj
      double pr = u1.re*u2.re - u1.im*u2.im;
      double pi = u1.re*u2.im + u1.im*u2.re;
      double rr = pr*u3re - pi*u3im;          // Re(u1*u2*conj(u3))
      if(rr == 0.0) continue;
      re += rr * cgc(l1,m1,l2,m2,l3,m3);
    }
  }
  return (float)re;
}

template<int L1,int L2,int L3>
constexpr std::array<float,(2*L1+1)*(2*L2+1)*(2*L3+1)> build_path(){
  std::array<float,(2*L1+1)*(2*L2+1)*(2*L3+1)> r{};
  for(int a=0;a<2*L1+1;++a)
    for(int b=0;b<2*L2+1;++b)
      for(int c=0;c<2*L3+1;++c)
        r[(a*(2*L2+1)+b)*(2*L3+1)+c] = crent(L1,L2,L3,a,b,c);
  return r;
}

} // namespace cgt

// ---------------------------------------------------------------------------
// Device helpers
// ---------------------------------------------------------------------------
__device__ constexpr int DEGA[25] = {0,1,1,1,2,2,2,2,2,3,3,3,3,3,3,3,4,4,4,4,4,4,4,4,4};

// u,v = deg_dense(y,W1), deg_dense(y,W2) for one degree block.
// y lives in LDS (B), read as uniform-address float4 broadcasts.
// W layout [d][f][g]: per-f row is 256B, coalesced across lanes (g = lane).
template<int D>
DEV void uv_deg(const float* __restrict__ B, const float* __restrict__ W1,
                const float* __restrict__ W2, int lane,
                float* __restrict__ u, float* __restrict__ v){
  constexpr int N = 2*D+1;
  float ua[N], va[N];
  #pragma unroll
  for(int m=0;m<N;++m){ ua[m]=0.0f; va[m]=0.0f; }
  const float* w1 = W1 + D*4096 + lane;
  const float* w2 = W2 + D*4096 + lane;
  for(int f0=0; f0<64; f0+=4){
    const float a0=w1[f0*64], a1=w1[(f0+1)*64], a2=w1[(f0+2)*64], a3=w1[(f0+3)*64];
    const float b0=w2[f0*64], b1=w2[(f0+1)*64], b2=w2[(f0+2)*64], b3=w2[(f0+3)*64];
    #pragma unroll
    for(int m=0;m<N;++m){
      const float4 yv = *(const float4*)(B + (D*D+m)*64 + f0);
      ua[m] = fmaf(yv.w,a3, fmaf(yv.z,a2, fmaf(yv.y,a1, fmaf(yv.x,a0, ua[m]))));
      va[m] = fmaf(yv.w,b3, fmaf(yv.z,b2, fmaf(yv.y,b1, fmaf(yv.x,b0, va[m]))));
    }
  }
  #pragma unroll
  for(int m=0;m<N;++m){ u[D*D+m]=ua[m]; v[D*D+m]=va[m]; }
}

template<int D>
DEV void out_deg(const float* __restrict__ B, const float* __restrict__ W,
                 int lane, float* __restrict__ yo){
  constexpr int N = 2*D+1;
  float acc[N];
  #pragma unroll
  for(int m=0;m<N;++m) acc[m]=0.0f;
  const float* w = W + D*4096 + lane;
  for(int f0=0; f0<64; f0+=4){
    const float a0=w[f0*64], a1=w[(f0+1)*64], a2=w[(f0+2)*64], a3=w[(f0+3)*64];
    #pragma unroll
    for(int m=0;m<N;++m){
      const float4 yv = *(const float4*)(B + (D*D+m)*64 + f0);
      acc[m] = fmaf(yv.w,a3, fmaf(yv.z,a2, fmaf(yv.y,a1, fmaf(yv.x,a0, acc[m]))));
    }
  }
  #pragma unroll
  for(int m=0;m<N;++m) yo[D*D+m]=acc[m];
}

// One CG path, fully unrolled; table entries fold to literals, zeros eliminated.
template<int L1,int L2,int L3,int P>
DEV void cg_path(const float* __restrict__ wp, int lane,
                 const float* __restrict__ u, const float* __restrict__ v,
                 float* __restrict__ t){
  constexpr auto C = cgt::build_path<L1,L2,L3>();
  const float wpv = wp[P*64 + lane];
  #pragma unroll
  for(int a=0;a<2*L1+1;++a){
    #pragma unroll
    for(int b=0;b<2*L2+1;++b){
      float uvw = 0.0f; bool made = false;
      #pragma unroll
      for(int c=0;c<2*L3+1;++c){
        const float cv = C[(a*(2*L2+1)+b)*(2*L3+1)+c];
        if(cv != 0.0f){
          if(!made){ uvw = u[L1*L1+a]*v[L2*L2+b]*wpv; made = true; }
          t[L3*L3+c] = fmaf(cv, uvw, t[L3*L3+c]);
        }
      }
    }
  }
}

DEV void cg_all(const float* __restrict__ wp, int lane,
                const float* __restrict__ u, const float* __restrict__ v,
                float* __restrict__ t){
  cg_path<0,0,0,0>(wp,lane,u,v,t);  cg_path<0,1,1,1>(wp,lane,u,v,t);
  cg_path<0,2,2,2>(wp,lane,u,v,t);  cg_path<0,3,3,3>(wp,lane,u,v,t);
  cg_path<0,4,4,4>(wp,lane,u,v,t);
  cg_path<1,0,1,5>(wp,lane,u,v,t);  cg_path<1,1,0,6>(wp,lane,u,v,t);
  cg_path<1,1,2,7>(wp,lane,u,v,t);  cg_path<1,2,1,8>(wp,lane,u,v,t);
  cg_path<1,2,3,9>(wp,lane,u,v,t);  cg_path<1,3,2,10>(wp,lane,u,v,t);
  cg_path<1,3,4,11>(wp,lane,u,v,t); cg_path<1,4,3,12>(wp,lane,u,v,t);
  cg_path<2,0,2,13>(wp,lane,u,v,t); cg_path<2,1,1,14>(wp,lane,u,v,t);
  cg_path<2,1,3,15>(wp,lane,u,v,t); cg_path<2,2,0,16>(wp,lane,u,v,t);
  cg_path<2,2,2,17>(wp,lane,u,v,t); cg_path<2,2,4,18>(wp,lane,u,v,t);
  cg_path<2,3,1,19>(wp,lane,u,v,t); cg_path<2,3,3,20>(wp,lane,u,v,t);
  cg_path<2,4,2,21>(wp,lane,u,v,t); cg_path<2,4,4,22>(wp,lane,u,v,t);
  cg_path<3,0,3,23>(wp,lane,u,v,t); cg_path<3,1,2,24>(wp,lane,u,v,t);
  cg_path<3,1,4,25>(wp,lane,u,v,t); cg_path<3,2,1,26>(wp,lane,u,v,t);
  cg_path<3,2,3,27>(wp,lane,u,v,t); cg_path<3,3,0,28>(wp,lane,u,v,t);
  cg_path<3,3,2,29>(wp,lane,u,v,t); cg_path<3,3,4,30>(wp,lane,u,v,t);
  cg_path<3,4,1,31>(wp,lane,u,v,t); cg_path<3,4,3,32>(wp,lane,u,v,t);
  cg_path<4,0,4,33>(wp,lane,u,v,t); cg_path<4,1,3,34>(wp,lane,u,v,t);
  cg_path<4,2,2,35>(wp,lane,u,v,t); cg_path<4,2,4,36>(wp,lane,u,v,t);
  cg_path<4,3,1,37>(wp,lane,u,v,t); cg_path<4,3,3,38>(wp,lane,u,v,t);
  cg_path<4,4,0,39>(wp,lane,u,v,t); cg_path<4,4,2,40>(wp,lane,u,v,t);
  cg_path<4,4,4,41>(wp,lane,u,v,t);
}

// ---------------------------------------------------------------------------
// Kernels
// ---------------------------------------------------------------------------
// A[s][g] = emb_table[s] @ W_emb_t  (species-deduped edge scale table)
__global__ void atab_kernel(const float* __restrict__ emb, const float* __restrict__ Wemb,
                            float* __restrict__ A){
  const int s = blockIdx.x;
  const int g = threadIdx.x;
  float acc = 0.0f;
  for(int f=0; f<64; ++f) acc = fmaf(emb[s*64+f], Wemb[f*64+g], acc);
  A[s*64+g] = acc;
}

// out[a,0,:] += A[Z[a]]  (runs after edge kernel; stream-ordered, one writer/elem)
__global__ void self_kernel(const int* __restrict__ an, const float* __restrict__ A,
                            float* __restrict__ out, int NA){
  const int i = blockIdx.x*256 + threadIdx.x;
  if(i < NA*64){
    const int a = i>>6, g = i&63;
    out[(size_t)a*1600 + g] += A[an[a]*64 + g];
  }
}

// One wave per edge (lane = feature). Full pipeline fused.
__global__ void __launch_bounds__(256) edge_kernel(
    const int* __restrict__ an, const int* __restrict__ nbr, const float* __restrict__ disp,
    const float* __restrict__ Wrad,
    const float* __restrict__ W1a, const float* __restrict__ W2a,
    const float* __restrict__ wpa, const float* __restrict__ Woa,
    const float* __restrict__ W1b, const float* __restrict__ W2b,
    const float* __restrict__ wpb, const float* __restrict__ Wob,
    const float* __restrict__ twt, const float* __restrict__ Atab,
    float* __restrict__ out, int NE)
{
  __shared__ __align__(16) float lds[4*1600];
  const int lane = threadIdx.x & 63;
  const int w    = threadIdx.x >> 6;
  const int e0   = blockIdx.x*4 + w;
  const bool active = e0 < NE;
  const int e = active ? e0 : 0;
  float* B = lds + w*1600;

  // ---- radial features -> y in LDS ----
  const int ai = nbr[2*e];
  const int aj = nbr[2*e+1];
  const float dx = disp[3*e], dy = disp[3*e+1], dz = disp[3*e+2];
  const float r  = sqrtf(fmaf(dx,dx,fmaf(dy,dy,dz*dz)) + 1e-12f);
  const float ir = 1.0f/r;
  const float x = dx*ir, y = dy*ir, z = dz*ir;
  const float fc = (r < 5.0f) ? (0.5f*(cosf(0.62831853071795864769f*r)+1.0f)) : 0.0f;

  const int Zj = an[aj];
  const float* Wr = Wrad + Zj*1024 + lane;
  float rad = 0.0f;
  #pragma unroll
  for(int k=0;k<16;++k){
    const float d  = r - (float)k*(1.0f/3.0f);
    const float rb = expf(-10.24f*d*d)*fc;
    rad = fmaf(rb, Wr[k*64], rad);
  }

  const float x2=x*x, y2=y*y, z2=z*z;
  float sh[25];
  sh[0]=0.28209479177387814f;
  sh[1]=0.4886025119029199f*y;
  sh[2]=0.4886025119029199f*z;
  sh[3]=0.4886025119029199f*x;
  sh[4]=1.0925484305920792f*x*y;
  sh[5]=1.0925484305920792f*y*z;
  sh[6]=0.31539156525252005f*(3.0f*z2-1.0f);
  sh[7]=1.0925484305920792f*x*z;
  sh[8]=0.5462742152960396f*(x2-y2);
  sh[9]=0.5900435899266435f*y*(3.0f*x2-y2);
  sh[10]=2.890611442640554f*x*y*z;
  sh[11]=0.4570457994644658f*y*(5.0f*z2-1.0f);
  sh[12]=0.3731763325901154f*z*(5.0f*z2-3.0f);
  sh[13]=0.4570457994644658f*x*(5.0f*z2-1.0f);
  sh[14]=1.445305721320277f*z*(x2-y2);
  sh[15]=0.5900435899266435f*x*(x2-3.0f*y2);
  sh[16]=2.5033429417967046f*x*y*(x2-y2);
  sh[17]=1.7701307697799304f*y*z*(3.0f*x2-y2);
  sh[18]=0.9461746957575601f*x*y*(7.0f*z2-1.0f);
  sh[19]=0.6690465435572892f*y*z*(7.0f*z2-3.0f);
  sh[20]=0.10578554691520431f*(35.0f*z2*z2-30.0f*z2+3.0f);
  sh[21]=0.6690465435572892f*x*z*(7.0f*z2-3.0f);
  sh[22]=0.47308734787878004f*(x2-y2)*(7.0f*z2-1.0f);
  sh[23]=1.7701307697799304f*x*z*(x2-3.0f*y2);
  sh[24]=0.6258357354491761f*(x2*x2-6.0f*x2*y2+y2*y2);

  #pragma unroll
  for(int lm=0;lm<25;++lm) B[lm*64+lane] = sh[lm]*rad;
  __syncthreads();

  // ---- two tensor-product layers ----
  #pragma unroll 1
  for(int L=0;L<2;++L){
    const float* W1 = L ? W1b : W1a;
    const float* W2 = L ? W2b : W2a;
    const float* wp = L ? wpb : wpa;
    const float* Wo = L ? Wob : Woa;

    float u[25], v[25];
    uv_deg<0>(B,W1,W2,lane,u,v);
    uv_deg<1>(B,W1,W2,lane,u,v);
    uv_deg<2>(B,W1,W2,lane,u,v);
    uv_deg<3>(B,W1,W2,lane,u,v);
    uv_deg<4>(B,W1,W2,lane,u,v);

    float t[25];
    #pragma unroll
    for(int i=0;i<25;++i) t[i]=0.0f;
    cg_all(wp,lane,u,v,t);

    __syncthreads();
    #pragma unroll
    for(int lm=0;lm<25;++lm) B[lm*64+lane] = t[lm];
    __syncthreads();

    float yn[25];
    out_deg<0>(B,Wo,lane,yn);
    out_deg<1>(B,Wo,lane,yn);
    out_deg<2>(B,Wo,lane,yn);
    out_deg<3>(B,Wo,lane,yn);
    out_deg<4>(B,Wo,lane,yn);

    __syncthreads();
    #pragma unroll
    for(int lm=0;lm<25;++lm) B[lm*64+lane] = yn[lm];
    __syncthreads();
  }

  // ---- scale + segment-sum ----
  if(active){
    const int Zi = an[ai];
    const float a = Atab[Zi*64+lane];
    float s[5];
    #pragma unroll
    for(int d=0;d<5;++d) s[d] = a*twt[d*64+lane];
    float* o = out + (size_t)ai*1600 + lane;
    #pragma unroll
    for(int lm=0;lm<25;++lm){
      atomicAdd(o + lm*64, B[lm*64+lane]*s[DEGA[lm]]);
    }
  }
}

// ---------------------------------------------------------------------------
extern "C" void kernel_launch(void* const* d_in, const int* in_sizes, int n_in,
                              void* d_out, int out_size, void* d_ws, size_t ws_size,
                              hipStream_t stream)
{
  const int*   an   = (const int*)  d_in[0];
  const int*   nbr  = (const int*)  d_in[1];
  const float* disp = (const float*)d_in[2];
  const float* emb  = (const float*)d_in[3];
  const float* Wemb = (const float*)d_in[4];
  const float* Wrad = (const float*)d_in[5];
  const float* W1a  = (const float*)d_in[6];
  const float* W2a  = (const float*)d_in[7];
  const float* wpa  = (const float*)d_in[8];
  const float* Woa  = (const float*)d_in[9];
  const float* W1b  = (const float*)d_in[10];
  const float* W2b  = (const float*)d_in[11];
  const float* wpb  = (const float*)d_in[12];
  const float* Wob  = (const float*)d_in[13];
  const float* twt  = (const float*)d_in[14];

  const int NA = in_sizes[0];
  const int NE = in_sizes[1]/2;
  const int NS = in_sizes[3]/64;

  float* Atab = (float*)d_ws;           // NS*64 floats of scratch
  float* out  = (float*)d_out;

  hipMemsetAsync(out, 0, (size_t)out_size*sizeof(float), stream);
  atab_kernel<<<NS, 64, 0, stream>>>(emb, Wemb, Atab);
  edge_kernel<<<(NE+3)/4, 256, 0, stream>>>(an, nbr, disp, Wrad,
                                            W1a, W2a, wpa, Woa,
                                            W1b, W2b, wpb, Wob,
                                            twt, Atab, out, NE);
  self_kernel<<<(NA*64+255)/256, 256, 0, stream>>>(an, Atab, out, NA);
}

// Round 2
// 3306.785 us; speedup vs baseline: 1.0063x; 1.0063x over previous
//
#include <hip/hip_runtime.h>
#include <array>

#define DEV __device__ __forceinline__

// ---------------------------------------------------------------------------
// Compile-time real Clebsch-Gordan tables (mirror of reference _build_paths)
// ---------------------------------------------------------------------------
namespace cgt {

constexpr double FACT[14] = {1.,1.,2.,6.,24.,120.,720.,5040.,40320.,362880.,
                             3628800.,39916800.,479001600.,6227020800.};

constexpr double csqrt(double x){
  if(x <= 0.0) return 0.0;
  double g = x > 1.0 ? x : 1.0;
  for(int i=0;i<28;++i) g = 0.5*(g + x/g);
  return g;
}

constexpr double cgc(int l1,int m1,int l2,int m2,int l3,int m3){
  if(m3 != m1+m2) return 0.0;
  double pre = (2.0*l3+1.0)*FACT[l1+l2-l3]*FACT[l1-l2+l3]*FACT[-l1+l2+l3]/FACT[l1+l2+l3+1];
  pre = csqrt(pre * FACT[l1+m1]*FACT[l1-m1]*FACT[l2+m2]*FACT[l2-m2]*FACT[l3+m3]*FACT[l3-m3]);
  double s = 0.0;
  for(int k=0;k<=l1+l2-l3;++k){
    int d1=l1+l2-l3-k, d2=l1-m1-k, d3=l2+m2-k, d4=l3-l2+m1+k, d5=l3-l1-m2+k;
    if(d1<0||d2<0||d3<0||d4<0||d5<0) continue;
    double den = FACT[k]*FACT[d1]*FACT[d2]*FACT[d3]*FACT[d4]*FACT[d5];
    s += ((k&1)? -1.0 : 1.0)/den;
  }
  return pre*s;
}

struct C2 { double re, im; };

// U_l[a, m+l] of the complex->real SH change of basis
constexpr C2 uent(int l, int a, int m){
  const double s = 0.70710678118654752440;
  int mr = a - l;
  if(mr == 0) return (m==0) ? C2{1.0,0.0} : C2{0.0,0.0};
  if(mr > 0){
    if(m ==  mr) return C2{ (mr&1)? -s : s, 0.0};
    if(m == -mr) return C2{ s, 0.0};
    return C2{0.0,0.0};
  }
  if(m ==  mr) return C2{0.0, s};
  if(m == -mr) return C2{0.0, ((-mr)&1)? s : -s};
  return C2{0.0,0.0};
}

constexpr float crent(int l1,int l2,int l3,int a,int b,int c){
  double re = 0.0;
  int mrc = c - l3;
  for(int i=0;i<2;++i){
    if(i==1 && a==l1) break;
    int m1 = (i==0) ? (a-l1) : (l1-a);
    for(int j=0;j<2;++j){
      if(j==1 && b==l2) break;
      int m2 = (j==0) ? (b-l2) : (l2-b);
      int m3 = m1+m2;
      if(m3 < -l3 || m3 > l3) continue;
      if(m3 != mrc && m3 != -mrc) continue;   // U3 row-c sparsity
      C2 u1 = uent(l1,a,m1), u2 = uent(l2,b,m2), u3 = uent(l3,c,m3);
      double u3re = u3.re, u3im = -u3.im;     // conj
      double pr = u1.re*u2.re - u1.im*u2.im;
      double pi = u1.re*u2.im + u1.im*u2.re;
      double rr = pr*u3re - pi*u3im;          // Re(u1*u2*conj(u3))
      if(rr == 0.0) continue;
      re += rr * cgc(l1,m1,l2,m2,l3,m3);
    }
  }
  return (float)re;
}

template<int L1,int L2,int L3>
constexpr std::array<float,(2*L1+1)*(2*L2+1)*(2*L3+1)> build_path(){
  std::array<float,(2*L1+1)*(2*L2+1)*(2*L3+1)> r{};
  for(int a=0;a<2*L1+1;++a)
    for(int b=0;b<2*L2+1;++b)
      for(int c=0;c<2*L3+1;++c)
        r[(a*(2*L2+1)+b)*(2*L3+1)+c] = crent(L1,L2,L3,a,b,c);
  return r;
}

} // namespace cgt

// ---------------------------------------------------------------------------
// Device helpers
// ---------------------------------------------------------------------------
__device__ constexpr int DEGA[25] = {0,1,1,1,2,2,2,2,2,3,3,3,3,3,3,3,4,4,4,4,4,4,4,4,4};

// u,v = deg_dense(y,W1), deg_dense(y,W2) for one degree block.
// y lives in LDS (B), read as uniform-address float4 broadcasts.
// W layout [d][f][g]: per-f row is 256B, coalesced across lanes (g = lane).
template<int D>
DEV void uv_deg(const float* __restrict__ B, const float* __restrict__ W1,
                const float* __restrict__ W2, int lane,
                float* __restrict__ u, float* __restrict__ v){
  constexpr int N = 2*D+1;
  float ua[N], va[N];
  #pragma unroll
  for(int m=0;m<N;++m){ ua[m]=0.0f; va[m]=0.0f; }
  const float* w1 = W1 + D*4096 + lane;
  const float* w2 = W2 + D*4096 + lane;
  for(int f0=0; f0<64; f0+=4){
    const float a0=w1[f0*64], a1=w1[(f0+1)*64], a2=w1[(f0+2)*64], a3=w1[(f0+3)*64];
    const float b0=w2[f0*64], b1=w2[(f0+1)*64], b2=w2[(f0+2)*64], b3=w2[(f0+3)*64];
    #pragma unroll
    for(int m=0;m<N;++m){
      const float4 yv = *(const float4*)(B + (D*D+m)*64 + f0);
      ua[m] = fmaf(yv.w,a3, fmaf(yv.z,a2, fmaf(yv.y,a1, fmaf(yv.x,a0, ua[m]))));
      va[m] = fmaf(yv.w,b3, fmaf(yv.z,b2, fmaf(yv.y,b1, fmaf(yv.x,b0, va[m]))));
    }
  }
  #pragma unroll
  for(int m=0;m<N;++m){ u[D*D+m]=ua[m]; v[D*D+m]=va[m]; }
}

template<int D>
DEV void out_deg(const float* __restrict__ B, const float* __restrict__ W,
                 int lane, float* __restrict__ yo){
  constexpr int N = 2*D+1;
  float acc[N];
  #pragma unroll
  for(int m=0;m<N;++m) acc[m]=0.0f;
  const float* w = W + D*4096 + lane;
  for(int f0=0; f0<64; f0+=4){
    const float a0=w[f0*64], a1=w[(f0+1)*64], a2=w[(f0+2)*64], a3=w[(f0+3)*64];
    #pragma unroll
    for(int m=0;m<N;++m){
      const float4 yv = *(const float4*)(B + (D*D+m)*64 + f0);
      acc[m] = fmaf(yv.w,a3, fmaf(yv.z,a2, fmaf(yv.y,a1, fmaf(yv.x,a0, acc[m]))));
    }
  }
  #pragma unroll
  for(int m=0;m<N;++m) yo[D*D+m]=acc[m];
}

// One CG path, fully unrolled; table entries fold to literals, zeros eliminated.
template<int L1,int L2,int L3,int P>
DEV void cg_path(const float* __restrict__ wp, int lane,
                 const float* __restrict__ u, const float* __restrict__ v,
                 float* __restrict__ t){
  constexpr auto C = cgt::build_path<L1,L2,L3>();
  const float wpv = wp[P*64 + lane];
  #pragma unroll
  for(int a=0;a<2*L1+1;++a){
    #pragma unroll
    for(int b=0;b<2*L2+1;++b){
      float uvw = 0.0f; bool made = false;
      #pragma unroll
      for(int c=0;c<2*L3+1;++c){
        const float cv = C[(a*(2*L2+1)+b)*(2*L3+1)+c];
        if(cv != 0.0f){
          if(!made){ uvw = u[L1*L1+a]*v[L2*L2+b]*wpv; made = true; }
          t[L3*L3+c] = fmaf(cv, uvw, t[L3*L3+c]);
        }
      }
    }
  }
}

DEV void cg_all(const float* __restrict__ wp, int lane,
                const float* __restrict__ u, const float* __restrict__ v,
                float* __restrict__ t){
  cg_path<0,0,0,0>(wp,lane,u,v,t);  cg_path<0,1,1,1>(wp,lane,u,v,t);
  cg_path<0,2,2,2>(wp,lane,u,v,t);  cg_path<0,3,3,3>(wp,lane,u,v,t);
  cg_path<0,4,4,4>(wp,lane,u,v,t);
  cg_path<1,0,1,5>(wp,lane,u,v,t);  cg_path<1,1,0,6>(wp,lane,u,v,t);
  cg_path<1,1,2,7>(wp,lane,u,v,t);  cg_path<1,2,1,8>(wp,lane,u,v,t);
  cg_path<1,2,3,9>(wp,lane,u,v,t);  cg_path<1,3,2,10>(wp,lane,u,v,t);
  cg_path<1,3,4,11>(wp,lane,u,v,t); cg_path<1,4,3,12>(wp,lane,u,v,t);
  cg_path<2,0,2,13>(wp,lane,u,v,t); cg_path<2,1,1,14>(wp,lane,u,v,t);
  cg_path<2,1,3,15>(wp,lane,u,v,t); cg_path<2,2,0,16>(wp,lane,u,v,t);
  cg_path<2,2,2,17>(wp,lane,u,v,t); cg_path<2,2,4,18>(wp,lane,u,v,t);
  cg_path<2,3,1,19>(wp,lane,u,v,t); cg_path<2,3,3,20>(wp,lane,u,v,t);
  cg_path<2,4,2,21>(wp,lane,u,v,t); cg_path<2,4,4,22>(wp,lane,u,v,t);
  cg_path<3,0,3,23>(wp,lane,u,v,t); cg_path<3,1,2,24>(wp,lane,u,v,t);
  cg_path<3,1,4,25>(wp,lane,u,v,t); cg_path<3,2,1,26>(wp,lane,u,v,t);
  cg_path<3,2,3,27>(wp,lane,u,v,t); cg_path<3,3,0,28>(wp,lane,u,v,t);
  cg_path<3,3,2,29>(wp,lane,u,v,t); cg_path<3,3,4,30>(wp,lane,u,v,t);
  cg_path<3,4,1,31>(wp,lane,u,v,t); cg_path<3,4,3,32>(wp,lane,u,v,t);
  cg_path<4,0,4,33>(wp,lane,u,v,t); cg_path<4,1,3,34>(wp,lane,u,v,t);
  cg_path<4,2,2,35>(wp,lane,u,v,t); cg_path<4,2,4,36>(wp,lane,u,v,t);
  cg_path<4,3,1,37>(wp,lane,u,v,t); cg_path<4,3,3,38>(wp,lane,u,v,t);
  cg_path<4,4,0,39>(wp,lane,u,v,t); cg_path<4,4,2,40>(wp,lane,u,v,t);
  cg_path<4,4,4,41>(wp,lane,u,v,t);
}

// ---------------------------------------------------------------------------
// Kernels
// ---------------------------------------------------------------------------
// A[s][g] = emb_table[s] @ W_emb_t  (species-deduped edge scale table)
__global__ void atab_kernel(const float* __restrict__ emb, const float* __restrict__ Wemb,
                            float* __restrict__ A){
  const int s = blockIdx.x;
  const int g = threadIdx.x;
  float acc = 0.0f;
  for(int f=0; f<64; ++f) acc = fmaf(emb[s*64+f], Wemb[f*64+g], acc);
  A[s*64+g] = acc;
}

// out[a,0,:] += A[Z[a]]  (runs after edge kernel; stream-ordered, one writer/elem)
__global__ void self_kernel(const int* __restrict__ an, const float* __restrict__ A,
                            float* __restrict__ out, int NA){
  const int i = blockIdx.x*256 + threadIdx.x;
  if(i < NA*64){
    const int a = i>>6, g = i&63;
    out[(size_t)a*1600 + g] += A[an[a]*64 + g];
  }
}

// One wave per edge (lane = feature). Full pipeline fused.
__global__ void __launch_bounds__(256) edge_kernel(
    const int* __restrict__ an, const int* __restrict__ nbr, const float* __restrict__ disp,
    const float* __restrict__ Wrad,
    const float* __restrict__ W1a, const float* __restrict__ W2a,
    const float* __restrict__ wpa, const float* __restrict__ Woa,
    const float* __restrict__ W1b, const float* __restrict__ W2b,
    const float* __restrict__ wpb, const float* __restrict__ Wob,
    const float* __restrict__ twt, const float* __restrict__ Atab,
    float* __restrict__ out, int NE)
{
  __shared__ __align__(16) float lds[4*1600];
  const int lane = threadIdx.x & 63;
  const int w    = threadIdx.x >> 6;
  const int e0   = blockIdx.x*4 + w;
  const bool active = e0 < NE;
  const int e = active ? e0 : 0;
  float* B = lds + w*1600;

  // ---- radial features -> y in LDS ----
  const int ai = nbr[2*e];
  const int aj = nbr[2*e+1];
  const float dx = disp[3*e], dy = disp[3*e+1], dz = disp[3*e+2];
  const float r  = sqrtf(fmaf(dx,dx,fmaf(dy,dy,dz*dz)) + 1e-12f);
  const float ir = 1.0f/r;
  const float x = dx*ir, y = dy*ir, z = dz*ir;
  const float fc = (r < 5.0f) ? (0.5f*(cosf(0.62831853071795864769f*r)+1.0f)) : 0.0f;

  const int Zj = an[aj];
  const float* Wr = Wrad + Zj*1024 + lane;
  float rad = 0.0f;
  #pragma unroll
  for(int k=0;k<16;++k){
    const float d  = r - (float)k*(1.0f/3.0f);
    const float rb = expf(-10.24f*d*d)*fc;
    rad = fmaf(rb, Wr[k*64], rad);
  }

  const float x2=x*x, y2=y*y, z2=z*z;
  float sh[25];
  sh[0]=0.28209479177387814f;
  sh[1]=0.4886025119029199f*y;
  sh[2]=0.4886025119029199f*z;
  sh[3]=0.4886025119029199f*x;
  sh[4]=1.0925484305920792f*x*y;
  sh[5]=1.0925484305920792f*y*z;
  sh[6]=0.31539156525252005f*(3.0f*z2-1.0f);
  sh[7]=1.0925484305920792f*x*z;
  sh[8]=0.5462742152960396f*(x2-y2);
  sh[9]=0.5900435899266435f*y*(3.0f*x2-y2);
  sh[10]=2.890611442640554f*x*y*z;
  sh[11]=0.4570457994644658f*y*(5.0f*z2-1.0f);
  sh[12]=0.3731763325901154f*z*(5.0f*z2-3.0f);
  sh[13]=0.4570457994644658f*x*(5.0f*z2-1.0f);
  sh[14]=1.445305721320277f*z*(x2-y2);
  sh[15]=0.5900435899266435f*x*(x2-3.0f*y2);
  sh[16]=2.5033429417967046f*x*y*(x2-y2);
  sh[17]=1.7701307697799304f*y*z*(3.0f*x2-y2);
  sh[18]=0.9461746957575601f*x*y*(7.0f*z2-1.0f);
  sh[19]=0.6690465435572892f*y*z*(7.0f*z2-3.0f);
  sh[20]=0.10578554691520431f*(35.0f*z2*z2-30.0f*z2+3.0f);
  sh[21]=0.6690465435572892f*x*z*(7.0f*z2-3.0f);
  sh[22]=0.47308734787878004f*(x2-y2)*(7.0f*z2-1.0f);
  sh[23]=1.7701307697799304f*x*z*(x2-3.0f*y2);
  sh[24]=0.6258357354491761f*(x2*x2-6.0f*x2*y2+y2*y2);

  #pragma unroll
  for(int lm=0;lm<25;++lm) B[lm*64+lane] = sh[lm]*rad;
  __syncthreads();

  // ---- two tensor-product layers ----
  #pragma unroll 1
  for(int L=0;L<2;++L){
    const float* W1 = L ? W1b : W1a;
    const float* W2 = L ? W2b : W2a;
    const float* wp = L ? wpb : wpa;
    const float* Wo = L ? Wob : Woa;

    float u[25], v[25];
    uv_deg<0>(B,W1,W2,lane,u,v);
    uv_deg<1>(B,W1,W2,lane,u,v);
    uv_deg<2>(B,W1,W2,lane,u,v);
    uv_deg<3>(B,W1,W2,lane,u,v);
    uv_deg<4>(B,W1,W2,lane,u,v);

    float t[25];
    #pragma unroll
    for(int i=0;i<25;++i) t[i]=0.0f;
    cg_all(wp,lane,u,v,t);

    __syncthreads();
    #pragma unroll
    for(int lm=0;lm<25;++lm) B[lm*64+lane] = t[lm];
    __syncthreads();

    float yn[25];
    out_deg<0>(B,Wo,lane,yn);
    out_deg<1>(B,Wo,lane,yn);
    out_deg<2>(B,Wo,lane,yn);
    out_deg<3>(B,Wo,lane,yn);
    out_deg<4>(B,Wo,lane,yn);

    __syncthreads();
    #pragma unroll
    for(int lm=0;lm<25;++lm) B[lm*64+lane] = yn[lm];
    __syncthreads();
  }

  // ---- scale + segment-sum ----
  if(active){
    const int Zi = an[ai];
    const float a = Atab[Zi*64+lane];
    float s[5];
    #pragma unroll
    for(int d=0;d<5;++d) s[d] = a*twt[d*64+lane];
    float* o = out + (size_t)ai*1600 + lane;
    #pragma unroll
    for(int lm=0;lm<25;++lm){
      atomicAdd(o + lm*64, B[lm*64+lane]*s[DEGA[lm]]);
    }
  }
}

// ---------------------------------------------------------------------------
extern "C" void kernel_launch(void* const* d_in, const int* in_sizes, int n_in,
                              void* d_out, int out_size, void* d_ws, size_t ws_size,
                              hipStream_t stream)
{
  const int*   an   = (const int*)  d_in[0];
  const int*   nbr  = (const int*)  d_in[1];
  const float* disp = (const float*)d_in[2];
  const float* emb  = (const float*)d_in[3];
  const float* Wemb = (const float*)d_in[4];
  const float* Wrad = (const float*)d_in[5];
  const float* W1a  = (const float*)d_in[6];
  const float* W2a  = (const float*)d_in[7];
  const float* wpa  = (const float*)d_in[8];
  const float* Woa  = (const float*)d_in[9];
  const float* W1b  = (const float*)d_in[10];
  const float* W2b  = (const float*)d_in[11];
  const float* wpb  = (const float*)d_in[12];
  const float* Wob  = (const float*)d_in[13];
  const float* twt  = (const float*)d_in[14];

  const int NA = in_sizes[0];
  const int NE = in_sizes[1]/2;
  const int NS = in_sizes[3]/64;

  float* Atab = (float*)d_ws;           // NS*64 floats of scratch
  float* out  = (float*)d_out;

  hipMemsetAsync(out, 0, (size_t)out_size*sizeof(float), stream);
  atab_kernel<<<NS, 64, 0, stream>>>(emb, Wemb, Atab);
  edge_kernel<<<(NE+3)/4, 256, 0, stream>>>(an, nbr, disp, Wrad,
                                            W1a, W2a, wpa, Woa,
                                            W1b, W2b, wpb, Wob,
                                            twt, Atab, out, NE);
  self_kernel<<<(NA*64+255)/256, 256, 0, stream>>>(an, Atab, out, NA);
}